// Round 2
// baseline (1430.345 us; speedup 1.0000x reference)
//
#include <hip/hip_runtime.h>
#include <hip/hip_bf16.h>
#include <cstdint>
#include <cstddef>

#define ALPHA 0.2f
#define MLP_SLOPE 0.01f

typedef short bf16x8 __attribute__((ext_vector_type(8)));
typedef float f32x4 __attribute__((ext_vector_type(4)));
typedef unsigned short ushort_t;

// raw barrier: syncs LDS exchange WITHOUT draining vmcnt (global prefetches
// stay in flight across it).
#define ASM_BARRIER() __asm__ __volatile__("s_waitcnt lgkmcnt(0)\n\ts_barrier" ::: "memory")

__device__ __forceinline__ float lrelu(float x, float s) { return x > 0.f ? x : x * s; }
__device__ __forceinline__ ushort_t f2bf(float x) {
  __hip_bfloat16 h = __float2bfloat16(x);
  return *reinterpret_cast<ushort_t*>(&h);
}
__device__ __forceinline__ float bf2f(ushort_t u) {
  union { unsigned int i; float f; } v; v.i = ((unsigned int)u) << 16; return v.f;
}

// ---------------------------------------------------------------------------
// cast fp32 -> bf16, 4 elems/thread
// ---------------------------------------------------------------------------
__global__ __launch_bounds__(256) void tobf(
    const float* __restrict__ in, ushort_t* __restrict__ outp)
{
  int idx = blockIdx.x * 256 + threadIdx.x;
  float4 v = ((const float4*)in)[idx];
  ushort4 h;
  h.x = f2bf(v.x); h.y = f2bf(v.y); h.z = f2bf(v.z); h.w = f2bf(v.w);
  ((ushort4*)outp)[idx] = h;
}

// ---------------------------------------------------------------------------
// zero a float buffer (s1/s2 init for atomics)
// ---------------------------------------------------------------------------
__global__ __launch_bounds__(256) void zero_f(float* __restrict__ p)
{
  int idx = blockIdx.x * 256 + threadIdx.x;
  ((float4*)p)[idx] = make_float4(0.f, 0.f, 0.f, 0.f);
}

// ---------------------------------------------------------------------------
// Pack weights W[K,N] (batch via blockIdx.y) into MFMA B-fragment order:
// frag(nblk,kblk) at ((nblk*(K/32)+kblk)*64+lane)*8; lo==nullptr -> hi only.
// ---------------------------------------------------------------------------
__global__ __launch_bounds__(256) void pack_wt(
    const float* __restrict__ W, ushort_t* __restrict__ hi,
    ushort_t* __restrict__ lo, int K, int N)
{
  int gid = blockIdx.x * 256 + threadIdx.x;   // [0, N*K/8)
  int lane = gid & 63;
  int kbc = K >> 5;
  int kblk = (gid >> 6) % kbc;
  int nblk = (gid >> 6) / kbc;
  size_t b = (size_t)blockIdx.y * K * N;
  int col = nblk * 16 + (lane & 15);
  int krow = kblk * 32 + (lane >> 4) * 8;
  ushort_t h[8] __attribute__((aligned(16)));
  ushort_t l[8] __attribute__((aligned(16)));
#pragma unroll
  for (int e = 0; e < 8; ++e) {
    float v = W[b + (size_t)(krow + e) * N + col];
    h[e] = f2bf(v);
    l[e] = f2bf(v - bf2f(h[e]));
  }
  *(uint4*)&hi[b + (size_t)gid * 8] = *(uint4*)h;
  if (lo) *(uint4*)&lo[b + (size_t)gid * 8] = *(uint4*)l;
}

// ---------------------------------------------------------------------------
// Fused h-GEMM: h = x@Wg (single-pass bf16), epilogue writes Bpack (B-frag
// order) + atomic s1/s2 dots. h never materialized in fp32.  (R9, frozen)
// ---------------------------------------------------------------------------
__global__ __launch_bounds__(256, 2) void gemm_h(
    const ushort_t* __restrict__ xb, const ushort_t* __restrict__ Wgp,
    const float* __restrict__ a1, const float* __restrict__ a2,
    ushort_t* __restrict__ Bpack, float* __restrict__ s1,
    float* __restrict__ s2)
{
  __shared__ ushort_t Ab[2][128][40];
  const int t = threadIdx.x;
  const int head = blockIdx.z;
  const int m0 = blockIdx.y * 128;
  const int n0 = blockIdx.x * 64;
  const int wave = t >> 6;
  const int wm = (wave & 1) * 64, wn = (wave >> 1) * 32;
  const int l16 = t & 15, quad = (t >> 4) & 3, l63 = t & 63;
  const int sr = t >> 1, sp = (t & 1) * 16;
  const ushort_t* arow_g = xb + (size_t)(m0 + sr) * 512 + sp;
  const ushort_t* bp = Wgp + (size_t)head * 256 * 512;
  const int nb0 = (n0 + wn) >> 4;

  f32x4 acc[4][2];
#pragma unroll
  for (int i = 0; i < 4; ++i)
#pragma unroll
    for (int j = 0; j < 2; ++j) acc[i][j] = (f32x4){0.f, 0.f, 0.f, 0.f};

  uint4 r0, r1;
  r0 = *(const uint4*)(arow_g);
  r1 = *(const uint4*)(arow_g + 8);
  *(uint4*)&Ab[0][sr][sp] = r0;
  *(uint4*)&Ab[0][sr][sp + 8] = r1;
  __syncthreads();

  for (int kb = 0; kb < 16; ++kb) {
    const int cur = kb & 1, nxt = cur ^ 1;
    if (kb < 15) {
      const ushort_t* p = arow_g + (kb + 1) * 32;
      r0 = *(const uint4*)p;
      r1 = *(const uint4*)(p + 8);
    }
    bf16x8 Bf[2];
#pragma unroll
    for (int nt = 0; nt < 2; ++nt)
      Bf[nt] = *(const bf16x8*)&bp[(((size_t)(nb0 + nt) * 16 + kb) * 64 + l63) * 8];
    bf16x8 Af[4];
#pragma unroll
    for (int mt = 0; mt < 4; ++mt)
      Af[mt] = *(const bf16x8*)&Ab[cur][wm + mt * 16 + l16][quad * 8];
#pragma unroll
    for (int mt = 0; mt < 4; ++mt)
#pragma unroll
      for (int nt = 0; nt < 2; ++nt)
        acc[mt][nt] = __builtin_amdgcn_mfma_f32_16x16x32_bf16(
            Af[mt], Bf[nt], acc[mt][nt], 0, 0, 0);
    if (kb < 15) {
      *(uint4*)&Ab[nxt][sr][sp] = r0;
      *(uint4*)&Ab[nxt][sr][sp + 8] = r1;
    }
    __syncthreads();
  }

  // ---- epilogue 1: write Bpack in B-fragment order (bf16) ----
#pragma unroll
  for (int mt = 0; mt < 4; ++mt)
#pragma unroll
    for (int nt = 0; nt < 2; ++nt)
#pragma unroll
      for (int rg = 0; rg < 4; ++rg) {
        int j = m0 + wm + mt * 16 + quad * 4 + rg;
        int c = n0 + wn + nt * 16 + l16;
        int kblk = j >> 5;
        int laneb = ((j >> 3) & 3) * 16 + (c & 15);
        int e = j & 7;
        Bpack[(((size_t)head * 256 + kblk) * 16 + (c >> 4)) * 512 + laneb * 8 + e] =
            f2bf(acc[mt][nt][rg]);
      }
  // ---- epilogue 2: s1/s2 partial dots, shuffle-reduced over 16 cols ----
  float a1v[2], a2v[2];
#pragma unroll
  for (int nt = 0; nt < 2; ++nt) {
    int c = n0 + wn + nt * 16 + l16;
    a1v[nt] = a1[head * 256 + c];
    a2v[nt] = a2[head * 256 + c];
  }
#pragma unroll
  for (int mt = 0; mt < 4; ++mt)
#pragma unroll
    for (int rg = 0; rg < 4; ++rg) {
      float p1 = acc[mt][0][rg] * a1v[0] + acc[mt][1][rg] * a1v[1];
      float p2 = acc[mt][0][rg] * a2v[0] + acc[mt][1][rg] * a2v[1];
      p1 += __shfl_xor(p1, 1); p2 += __shfl_xor(p2, 1);
      p1 += __shfl_xor(p1, 2); p2 += __shfl_xor(p2, 2);
      p1 += __shfl_xor(p1, 4); p2 += __shfl_xor(p2, 4);
      p1 += __shfl_xor(p1, 8); p2 += __shfl_xor(p2, 8);
      if (l16 == 0) {
        int row = m0 + wm + mt * 16 + quad * 4 + rg;
        atomicAdd(&s1[head * 8192 + row], p1);
        atomicAdd(&s2[head * 8192 + row], p2);
      }
    }
}

// ---------------------------------------------------------------------------
// Pipelined split-bf16 MLP GEMM (R9, frozen).
// ---------------------------------------------------------------------------
__global__ __launch_bounds__(256, 2) void gemm_mlp(
    const ushort_t* __restrict__ Ahi, const ushort_t* __restrict__ Alo,
    const ushort_t* __restrict__ Bph, const ushort_t* __restrict__ Bpl,
    const float* __restrict__ bias, float* __restrict__ Cf,
    ushort_t* __restrict__ Chi, ushort_t* __restrict__ Clo,
    int M, int N, int K, float slope)
{
  __shared__ ushort_t Ah[2][128][40], Al[2][128][40];
  const int kbc = K >> 5;
  const int t = threadIdx.x;
  const int m0 = blockIdx.y * 128;
  const int n0 = blockIdx.x * 64;
  const int wave = t >> 6;
  const int wm = (wave & 1) * 64, wn = (wave >> 1) * 32;
  const int l16 = t & 15, quad = (t >> 4) & 3, l63 = t & 63;
  const int sr = t >> 1, sp = (t & 1) * 16;
  const ushort_t* ah_g = Ahi + (size_t)(m0 + sr) * K + sp;
  const ushort_t* al_g = Alo + (size_t)(m0 + sr) * K + sp;
  const int nb0 = (n0 + wn) >> 4;

  f32x4 acc[4][2];
#pragma unroll
  for (int i = 0; i < 4; ++i)
#pragma unroll
    for (int j = 0; j < 2; ++j) acc[i][j] = (f32x4){0.f, 0.f, 0.f, 0.f};

  uint4 rh0, rh1, rl0, rl1;
  rh0 = *(const uint4*)(ah_g);
  rh1 = *(const uint4*)(ah_g + 8);
  rl0 = *(const uint4*)(al_g);
  rl1 = *(const uint4*)(al_g + 8);
  *(uint4*)&Ah[0][sr][sp] = rh0;
  *(uint4*)&Ah[0][sr][sp + 8] = rh1;
  *(uint4*)&Al[0][sr][sp] = rl0;
  *(uint4*)&Al[0][sr][sp + 8] = rl1;
  __syncthreads();

  for (int kb = 0; kb < kbc; ++kb) {
    const int cur = kb & 1, nxt = cur ^ 1;
    if (kb + 1 < kbc) {
      const ushort_t* ph = ah_g + (kb + 1) * 32;
      const ushort_t* plo = al_g + (kb + 1) * 32;
      rh0 = *(const uint4*)ph;
      rh1 = *(const uint4*)(ph + 8);
      rl0 = *(const uint4*)plo;
      rl1 = *(const uint4*)(plo + 8);
    }
    bf16x8 bh[2], bl[2];
#pragma unroll
    for (int nt = 0; nt < 2; ++nt) {
      size_t o = (((size_t)(nb0 + nt) * kbc + kb) * 64 + l63) * 8;
      bh[nt] = *(const bf16x8*)&Bph[o];
      bl[nt] = *(const bf16x8*)&Bpl[o];
    }
    bf16x8 afh[4], afl[4];
#pragma unroll
    for (int mt = 0; mt < 4; ++mt) {
      afh[mt] = *(const bf16x8*)&Ah[cur][wm + mt * 16 + l16][quad * 8];
      afl[mt] = *(const bf16x8*)&Al[cur][wm + mt * 16 + l16][quad * 8];
    }
#pragma unroll
    for (int mt = 0; mt < 4; ++mt)
#pragma unroll
      for (int nt = 0; nt < 2; ++nt) {
        acc[mt][nt] = __builtin_amdgcn_mfma_f32_16x16x32_bf16(afh[mt], bh[nt], acc[mt][nt], 0, 0, 0);
        acc[mt][nt] = __builtin_amdgcn_mfma_f32_16x16x32_bf16(afh[mt], bl[nt], acc[mt][nt], 0, 0, 0);
        acc[mt][nt] = __builtin_amdgcn_mfma_f32_16x16x32_bf16(afl[mt], bh[nt], acc[mt][nt], 0, 0, 0);
      }
    if (kb + 1 < kbc) {
      *(uint4*)&Ah[nxt][sr][sp] = rh0;
      *(uint4*)&Ah[nxt][sr][sp + 8] = rh1;
      *(uint4*)&Al[nxt][sr][sp] = rl0;
      *(uint4*)&Al[nxt][sr][sp + 8] = rl1;
    }
    __syncthreads();
  }

#pragma unroll
  for (int mt = 0; mt < 4; ++mt)
#pragma unroll
    for (int nt = 0; nt < 2; ++nt)
#pragma unroll
      for (int rg = 0; rg < 4; ++rg) {
        int m = m0 + wm + mt * 16 + quad * 4 + rg;
        int n = n0 + wn + nt * 16 + l16;
        float v = lrelu(acc[mt][nt][rg] + bias[n], slope);
        size_t o = (size_t)m * N + n;
        if (Cf) Cf[o] = v;
        if (Chi) {
          ushort_t h = f2bf(v);
          Chi[o] = h; Clo[o] = f2bf(v - bf2f(h));
        }
      }
}

// ---------------------------------------------------------------------------
// MFMA attention v9: js split 4 -> 8 => grid 64x8 = 512 blocks = 2/CU.
// R1 profile showed v8 latency-bound: MfmaUtil 17%, VALUBusy 28%, HBM 16%,
// occupancy 21.8% (1 block/CU, barrier every kt couples all 8 waves).
// 2 blocks/CU (VGPR<=128 via launch_bounds(512,4), LDS 2x32KB) lets one
// block's waves issue while the other sits in barrier/vmcnt stalls.
// Per block: 32 kt steps over a 1024-col slice. pacc/pl: 16 slices.
// ---------------------------------------------------------------------------
__global__ __launch_bounds__(512, 4) void attn_mfma8(
    const ushort_t* __restrict__ Bpack, const float* __restrict__ s1g,
    const float* __restrict__ s2g, const int* __restrict__ adj,
    ushort_t* __restrict__ pacc, float* __restrict__ pl)
{
  __shared__ ushort_t Wlds[2][2][8][64][8];   // [buf][head][mt8][lane][8]
  const int t = threadIdx.x;
  const int i0 = blockIdx.x * 128;
  const int js = blockIdx.y;
  const int kbase = js * 1024;
  // generator mapping: row wr (0..127), k-octet kq (0..3)
  const int wr = t >> 2, kq = t & 3;
  const int glane = kq * 16 + (wr & 15);
  const int gmt = wr >> 4;                    // 0..7
  const float s1v0 = s1g[i0 + wr];
  const float s1v1 = s1g[8192 + i0 + wr];
  // consumer mapping: wave = (head, nh, rowgrp)
  const int wave = t >> 6;
  const int head = wave >> 2, nh = (wave >> 1) & 1, rg2 = wave & 1;
  const int l16 = t & 15, quad = (t >> 4) & 3;
  const int l63 = t & 63;
  f32x4 acc[4][8];
#pragma unroll
  for (int m = 0; m < 4; ++m)
#pragma unroll
    for (int n = 0; n < 8; ++n) acc[m][n] = (f32x4){0.f, 0.f, 0.f, 0.f};
  float rs0 = 0.f, rs1 = 0.f;

  const int* arow = adj + (size_t)(i0 + wr) * 8192;
  int4 pa0, pa1;
  float4 p20a, p20b, p21a, p21b;

  auto fetch = [&](int kk) {
    pa0 = *(const int4*)&arow[kk];
    pa1 = *(const int4*)&arow[kk + 4];
    p20a = *(const float4*)&s2g[kk];
    p20b = *(const float4*)&s2g[kk + 4];
    p21a = *(const float4*)&s2g[8192 + kk];
    p21b = *(const float4*)&s2g[8192 + kk + 4];
  };
  auto gen = [&](int buf) {
    int am[8] = {pa0.x, pa0.y, pa0.z, pa0.w, pa1.x, pa1.y, pa1.z, pa1.w};
    float s20[8] = {p20a.x, p20a.y, p20a.z, p20a.w, p20b.x, p20b.y, p20b.z, p20b.w};
    float s21[8] = {p21a.x, p21a.y, p21a.z, p21a.w, p21b.x, p21b.y, p21b.z, p21b.w};
    ushort_t w0[8] __attribute__((aligned(16)));
    ushort_t w1[8] __attribute__((aligned(16)));
#pragma unroll
    for (int e = 0; e < 8; ++e) {
      float e0 = s1v0 + s20[e];
      float e1 = s1v1 + s21[e];
      e0 = fmaxf(e0, 0.f) + ALPHA * fminf(e0, 0.f);
      e1 = fmaxf(e1, 0.f) + ALPHA * fminf(e1, 0.f);
      float v0 = am[e] > 0 ? __expf(e0) : 0.f;
      float v1 = am[e] > 0 ? __expf(e1) : 0.f;
      rs0 += v0; rs1 += v1;
      w0[e] = f2bf(v0); w1[e] = f2bf(v1);
    }
    *(uint4*)&Wlds[buf][0][gmt][glane][0] = *(uint4*)w0;
    *(uint4*)&Wlds[buf][1][gmt][glane][0] = *(uint4*)w1;
  };

  fetch(kbase + kq * 8);
  gen(0);
  fetch(kbase + 32 + kq * 8);
  ASM_BARRIER();

  for (int kt = 0; kt < 32; ++kt) {
    const int cur = kt & 1, nxt = cur ^ 1;
    const int kblk = js * 32 + kt;
    const ushort_t* bb =
        Bpack + ((((size_t)head * 256 + kblk) * 16 + nh * 8) * 64 + l63) * 8;
    bf16x8 Bf[8];
#pragma unroll
    for (int nt = 0; nt < 8; ++nt)
      Bf[nt] = *(const bf16x8*)&bb[nt * 512];
    bf16x8 Af[4];
#pragma unroll
    for (int mt = 0; mt < 4; ++mt)
      Af[mt] = *(const bf16x8*)&Wlds[cur][head][rg2 * 4 + mt][l63][0];
#pragma unroll
    for (int mt = 0; mt < 4; ++mt)
#pragma unroll
      for (int nt = 0; nt < 8; ++nt)
        acc[mt][nt] = __builtin_amdgcn_mfma_f32_16x16x32_bf16(
            Af[mt], Bf[nt], acc[mt][nt], 0, 0, 0);
    if (kt < 31) {
      gen(nxt);
      if (kt < 30) fetch(kbase + (kt + 2) * 32 + kq * 8);
    }
    ASM_BARRIER();
  }

  // denominators: reduce across the 4 kq lanes of each row
  rs0 += __shfl_xor(rs0, 1); rs0 += __shfl_xor(rs0, 2);
  rs1 += __shfl_xor(rs1, 1); rs1 += __shfl_xor(rs1, 2);
  if (kq == 0) {
    pl[((size_t)js * 2 + 0) * 8192 + i0 + wr] = rs0;
    pl[((size_t)js * 2 + 1) * 8192 + i0 + wr] = rs1;
  }
  // store bf16 partial numerators
  const int n0 = nh * 128;
#pragma unroll
  for (int mt = 0; mt < 4; ++mt)
#pragma unroll
    for (int nt = 0; nt < 8; ++nt)
#pragma unroll
      for (int rg = 0; rg < 4; ++rg) {
        int row = i0 + rg2 * 64 + mt * 16 + quad * 4 + rg;
        int col = n0 + nt * 16 + l16;
        pacc[(((size_t)js * 2 + head) * 8192 + row) * 256 + col] =
            f2bf(acc[mt][nt][rg]);
      }
}

// ---------------------------------------------------------------------------
// Finalize: emits embed directly as hi/lo bf16 split. Now sums 8 js slices.
// ---------------------------------------------------------------------------
__global__ __launch_bounds__(256) void attn_finalize(
    const ushort_t* __restrict__ pacc, const float* __restrict__ pl,
    const float* __restrict__ bg, const float* __restrict__ llm,
    ushort_t* __restrict__ ehi, ushort_t* __restrict__ elo)
{
  __shared__ float red[8];
  const int r = blockIdx.x;
  const int t = threadIdx.x;
  const int wv = t >> 6, lane = t & 63;
#pragma unroll
  for (int half = 0; half < 2; ++half) {
    float lv = llm[(size_t)r * 512 + half * 256 + t];
    ushort_t h = f2bf(lv);
    ehi[(size_t)r * 768 + half * 256 + t] = h;
    elo[(size_t)r * 768 + half * 256 + t] = f2bf(lv - bf2f(h));
  }
  float o[2];
#pragma unroll
  for (int hh = 0; hh < 2; ++hh) {
    float num = 0.f, l = 0.f;
#pragma unroll
    for (int js = 0; js < 8; ++js) {
      num += bf2f(pacc[(((size_t)js * 2 + hh) * 8192 + r) * 256 + t]);
      l += pl[((size_t)js * 2 + hh) * 8192 + r];
    }
    o[hh] = lrelu(num / l, ALPHA);
  }
  float v0 = o[0] * o[0], v1 = o[1] * o[1];
  for (int off = 32; off > 0; off >>= 1) {
    v0 += __shfl_xor(v0, off);
    v1 += __shfl_xor(v1, off);
  }
  if (lane == 0) { red[wv] = v0; red[4 + wv] = v1; }
  __syncthreads();
  float n0 = fmaxf(sqrtf(red[0] + red[1] + red[2] + red[3]), 1e-12f);
  float n1 = fmaxf(sqrtf(red[4] + red[5] + red[6] + red[7]), 1e-12f);
  float val = 0.5f * (o[0] / n0 + bg[t] + o[1] / n1 + bg[256 + t]);
  ushort_t h = f2bf(val);
  ehi[(size_t)r * 768 + 512 + t] = h;
  elo[(size_t)r * 768 + 512 + t] = f2bf(val - bf2f(h));
}

// ---------------------------------------------------------------------------
__global__ __launch_bounds__(256) void pred_kernel(
    const float* __restrict__ z2, const int* __restrict__ ts,
    float* __restrict__ out, int E)
{
  const int gw = (blockIdx.x * 256 + threadIdx.x) >> 6;
  const int lane = threadIdx.x & 63;
  if (gw >= E) return;
  const int a = ts[gw * 2], b = ts[gw * 2 + 1];
  float4 va = ((const float4*)(z2 + (size_t)a * 256))[lane];
  float4 vb = ((const float4*)(z2 + (size_t)b * 256))[lane];
  float p = va.x * vb.x + va.y * vb.y + va.z * vb.z + va.w * vb.w;
  for (int off = 32; off > 0; off >>= 1) p += __shfl_xor(p, off);
  if (lane == 0) out[gw] = p;
}

// ---------------------------------------------------------------------------
extern "C" void kernel_launch(void* const* d_in, const int* in_sizes, int n_in,
                              void* d_out, int out_size, void* d_ws, size_t ws_size,
                              hipStream_t stream) {
  const float* x   = (const float*)d_in[0];
  const int*   adj = (const int*)d_in[1];
  const int*   ts  = (const int*)d_in[2];
  const float* llm = (const float*)d_in[3];
  const float* Wg  = (const float*)d_in[4];
  const float* a1  = (const float*)d_in[5];
  const float* a2  = (const float*)d_in[6];
  const float* bg  = (const float*)d_in[7];
  const float* W1  = (const float*)d_in[8];
  const float* b1  = (const float*)d_in[9];
  const float* W2  = (const float*)d_in[10];
  const float* b2  = (const float*)d_in[11];
  float* out = (float*)d_out;
  float* ws  = (float*)d_ws;
  const int E = in_sizes[2] / 2;

  // ---- workspace layout (float words) ----
  ushort_t* xb    = (ushort_t*)(ws + 0);            //  8192x512 bf16
  ushort_t* Wgp   = (ushort_t*)(ws + 2097152);      //  2x512x256
  ushort_t* W1ph  = (ushort_t*)(ws + 2228224);      //  768x512
  ushort_t* W1pl  = (ushort_t*)(ws + 2424832);
  ushort_t* W2ph  = (ushort_t*)(ws + 2621440);      //  512x256
  ushort_t* W2pl  = (ushort_t*)(ws + 2686976);
  ushort_t* Bpack = (ushort_t*)(ws + 2752512);      //  2x8192x256
  float*    s1    = ws + 4849664;                   //  2x8192
  float*    s2    = ws + 4866048;
  float*    pl    = ws + 4882432;                   //  16x8192
  ushort_t* pacc  = (ushort_t*)(ws + 5013504);      //  16x8192x256 bf16
  ushort_t* ehi   = (ushort_t*)(ws + 21790720);     //  8192x768
  ushort_t* elo   = (ushort_t*)(ws + 24936448);
  ushort_t* z1hi  = (ushort_t*)(ws + 28082176);     //  8192x512
  ushort_t* z1lo  = (ushort_t*)(ws + 30179328);
  float*    z2    = ws + 32276480;                  //  8192x256 f32

  // 1. prep: casts, weight packing, s-zero
  tobf<<<4096, 256, 0, stream>>>(x, xb);
  pack_wt<<<dim3(64, 2), 256, 0, stream>>>(Wg, Wgp, nullptr, 512, 256);
  pack_wt<<<dim3(192, 1), 256, 0, stream>>>(W1, W1ph, W1pl, 768, 512);
  pack_wt<<<dim3(64, 1), 256, 0, stream>>>(W2, W2ph, W2pl, 512, 256);
  zero_f<<<32, 256, 0, stream>>>(s1);   // covers s1 and s2 (contiguous)
  // 2. fused h-GEMM -> Bpack + s1/s2 (hbuf never materialized)
  gemm_h<<<dim3(4, 64, 2), 256, 0, stream>>>(xb, Wgp, a1, a2, Bpack, s1, s2);
  // 3. MFMA attention partials (512 blocks = 2/CU for latency overlap)
  attn_mfma8<<<dim3(64, 8), 512, 0, stream>>>(Bpack, s1, s2, adj, pacc, pl);
  // 4. finalize -> embed emitted directly as hi/lo split (llm inline)
  attn_finalize<<<8192, 256, 0, stream>>>(pacc, pl, bg, llm, ehi, elo);
  // 5. z1 = LR(embed @ W1 + b1) -> hi/lo
  gemm_mlp<<<dim3(8, 64), 256, 0, stream>>>(
      ehi, elo, W1ph, W1pl, b1, nullptr, z1hi, z1lo, 8192, 512, 768, MLP_SLOPE);
  // 6. z2 = LR(z1 @ W2 + b2) -> fp32
  gemm_mlp<<<dim3(4, 64), 256, 0, stream>>>(
      z1hi, z1lo, W2ph, W2pl, b2, z2, nullptr, nullptr, 8192, 256, 512, MLP_SLOPE);
  // 7. edge dots
  pred_kernel<<<(E * 64 + 255) / 256, 256, 0, stream>>>(z2, ts, out, E);
}

// Round 3
// 584.369 us; speedup vs baseline: 2.4477x; 2.4477x over previous
//
#include <hip/hip_runtime.h>
#include <hip/hip_bf16.h>
#include <cstdint>
#include <cstddef>

#define ALPHA 0.2f
#define MLP_SLOPE 0.01f

typedef short bf16x8 __attribute__((ext_vector_type(8)));
typedef float f32x4 __attribute__((ext_vector_type(4)));
typedef unsigned short ushort_t;

// raw barrier: syncs LDS exchange WITHOUT draining vmcnt (global prefetches
// stay in flight across it).
#define ASM_BARRIER() __asm__ __volatile__("s_waitcnt lgkmcnt(0)\n\ts_barrier" ::: "memory")

__device__ __forceinline__ float lrelu(float x, float s) { return x > 0.f ? x : x * s; }
__device__ __forceinline__ ushort_t f2bf(float x) {
  __hip_bfloat16 h = __float2bfloat16(x);
  return *reinterpret_cast<ushort_t*>(&h);
}
__device__ __forceinline__ float bf2f(ushort_t u) {
  union { unsigned int i; float f; } v; v.i = ((unsigned int)u) << 16; return v.f;
}

// ---------------------------------------------------------------------------
// cast fp32 -> bf16, 4 elems/thread
// ---------------------------------------------------------------------------
__global__ __launch_bounds__(256) void tobf(
    const float* __restrict__ in, ushort_t* __restrict__ outp)
{
  int idx = blockIdx.x * 256 + threadIdx.x;
  float4 v = ((const float4*)in)[idx];
  ushort4 h;
  h.x = f2bf(v.x); h.y = f2bf(v.y); h.z = f2bf(v.z); h.w = f2bf(v.w);
  ((ushort4*)outp)[idx] = h;
}

// ---------------------------------------------------------------------------
// zero a float buffer (s1/s2 init for atomics)
// ---------------------------------------------------------------------------
__global__ __launch_bounds__(256) void zero_f(float* __restrict__ p)
{
  int idx = blockIdx.x * 256 + threadIdx.x;
  ((float4*)p)[idx] = make_float4(0.f, 0.f, 0.f, 0.f);
}

// ---------------------------------------------------------------------------
// Pack weights W[K,N] (batch via blockIdx.y) into MFMA B-fragment order:
// frag(nblk,kblk) at ((nblk*(K/32)+kblk)*64+lane)*8; lo==nullptr -> hi only.
// ---------------------------------------------------------------------------
__global__ __launch_bounds__(256) void pack_wt(
    const float* __restrict__ W, ushort_t* __restrict__ hi,
    ushort_t* __restrict__ lo, int K, int N)
{
  int gid = blockIdx.x * 256 + threadIdx.x;   // [0, N*K/8)
  int lane = gid & 63;
  int kbc = K >> 5;
  int kblk = (gid >> 6) % kbc;
  int nblk = (gid >> 6) / kbc;
  size_t b = (size_t)blockIdx.y * K * N;
  int col = nblk * 16 + (lane & 15);
  int krow = kblk * 32 + (lane >> 4) * 8;
  ushort_t h[8] __attribute__((aligned(16)));
  ushort_t l[8] __attribute__((aligned(16)));
#pragma unroll
  for (int e = 0; e < 8; ++e) {
    float v = W[b + (size_t)(krow + e) * N + col];
    h[e] = f2bf(v);
    l[e] = f2bf(v - bf2f(h[e]));
  }
  *(uint4*)&hi[b + (size_t)gid * 8] = *(uint4*)h;
  if (lo) *(uint4*)&lo[b + (size_t)gid * 8] = *(uint4*)l;
}

// ---------------------------------------------------------------------------
// Fused h-GEMM: h = x@Wg (single-pass bf16), epilogue writes Bpack (B-frag
// order) + atomic s1/s2 dots. h never materialized in fp32.  (R9, frozen)
// ---------------------------------------------------------------------------
__global__ __launch_bounds__(256, 2) void gemm_h(
    const ushort_t* __restrict__ xb, const ushort_t* __restrict__ Wgp,
    const float* __restrict__ a1, const float* __restrict__ a2,
    ushort_t* __restrict__ Bpack, float* __restrict__ s1,
    float* __restrict__ s2)
{
  __shared__ ushort_t Ab[2][128][40];
  const int t = threadIdx.x;
  const int head = blockIdx.z;
  const int m0 = blockIdx.y * 128;
  const int n0 = blockIdx.x * 64;
  const int wave = t >> 6;
  const int wm = (wave & 1) * 64, wn = (wave >> 1) * 32;
  const int l16 = t & 15, quad = (t >> 4) & 3, l63 = t & 63;
  const int sr = t >> 1, sp = (t & 1) * 16;
  const ushort_t* arow_g = xb + (size_t)(m0 + sr) * 512 + sp;
  const ushort_t* bp = Wgp + (size_t)head * 256 * 512;
  const int nb0 = (n0 + wn) >> 4;

  f32x4 acc[4][2];
#pragma unroll
  for (int i = 0; i < 4; ++i)
#pragma unroll
    for (int j = 0; j < 2; ++j) acc[i][j] = (f32x4){0.f, 0.f, 0.f, 0.f};

  uint4 r0, r1;
  r0 = *(const uint4*)(arow_g);
  r1 = *(const uint4*)(arow_g + 8);
  *(uint4*)&Ab[0][sr][sp] = r0;
  *(uint4*)&Ab[0][sr][sp + 8] = r1;
  __syncthreads();

  for (int kb = 0; kb < 16; ++kb) {
    const int cur = kb & 1, nxt = cur ^ 1;
    if (kb < 15) {
      const ushort_t* p = arow_g + (kb + 1) * 32;
      r0 = *(const uint4*)p;
      r1 = *(const uint4*)(p + 8);
    }
    bf16x8 Bf[2];
#pragma unroll
    for (int nt = 0; nt < 2; ++nt)
      Bf[nt] = *(const bf16x8*)&bp[(((size_t)(nb0 + nt) * 16 + kb) * 64 + l63) * 8];
    bf16x8 Af[4];
#pragma unroll
    for (int mt = 0; mt < 4; ++mt)
      Af[mt] = *(const bf16x8*)&Ab[cur][wm + mt * 16 + l16][quad * 8];
#pragma unroll
    for (int mt = 0; mt < 4; ++mt)
#pragma unroll
      for (int nt = 0; nt < 2; ++nt)
        acc[mt][nt] = __builtin_amdgcn_mfma_f32_16x16x32_bf16(
            Af[mt], Bf[nt], acc[mt][nt], 0, 0, 0);
    if (kb < 15) {
      *(uint4*)&Ab[nxt][sr][sp] = r0;
      *(uint4*)&Ab[nxt][sr][sp + 8] = r1;
    }
    __syncthreads();
  }

  // ---- epilogue 1: write Bpack in B-fragment order (bf16) ----
#pragma unroll
  for (int mt = 0; mt < 4; ++mt)
#pragma unroll
    for (int nt = 0; nt < 2; ++nt)
#pragma unroll
      for (int rg = 0; rg < 4; ++rg) {
        int j = m0 + wm + mt * 16 + quad * 4 + rg;
        int c = n0 + wn + nt * 16 + l16;
        int kblk = j >> 5;
        int laneb = ((j >> 3) & 3) * 16 + (c & 15);
        int e = j & 7;
        Bpack[(((size_t)head * 256 + kblk) * 16 + (c >> 4)) * 512 + laneb * 8 + e] =
            f2bf(acc[mt][nt][rg]);
      }
  // ---- epilogue 2: s1/s2 partial dots, shuffle-reduced over 16 cols ----
  float a1v[2], a2v[2];
#pragma unroll
  for (int nt = 0; nt < 2; ++nt) {
    int c = n0 + wn + nt * 16 + l16;
    a1v[nt] = a1[head * 256 + c];
    a2v[nt] = a2[head * 256 + c];
  }
#pragma unroll
  for (int mt = 0; mt < 4; ++mt)
#pragma unroll
    for (int rg = 0; rg < 4; ++rg) {
      float p1 = acc[mt][0][rg] * a1v[0] + acc[mt][1][rg] * a1v[1];
      float p2 = acc[mt][0][rg] * a2v[0] + acc[mt][1][rg] * a2v[1];
      p1 += __shfl_xor(p1, 1); p2 += __shfl_xor(p2, 1);
      p1 += __shfl_xor(p1, 2); p2 += __shfl_xor(p2, 2);
      p1 += __shfl_xor(p1, 4); p2 += __shfl_xor(p2, 4);
      p1 += __shfl_xor(p1, 8); p2 += __shfl_xor(p2, 8);
      if (l16 == 0) {
        int row = m0 + wm + mt * 16 + quad * 4 + rg;
        atomicAdd(&s1[head * 8192 + row], p1);
        atomicAdd(&s2[head * 8192 + row], p2);
      }
    }
}

// ---------------------------------------------------------------------------
// Pipelined split-bf16 MLP GEMM (R9, frozen).
// ---------------------------------------------------------------------------
__global__ __launch_bounds__(256, 2) void gemm_mlp(
    const ushort_t* __restrict__ Ahi, const ushort_t* __restrict__ Alo,
    const ushort_t* __restrict__ Bph, const ushort_t* __restrict__ Bpl,
    const float* __restrict__ bias, float* __restrict__ Cf,
    ushort_t* __restrict__ Chi, ushort_t* __restrict__ Clo,
    int M, int N, int K, float slope)
{
  __shared__ ushort_t Ah[2][128][40], Al[2][128][40];
  const int kbc = K >> 5;
  const int t = threadIdx.x;
  const int m0 = blockIdx.y * 128;
  const int n0 = blockIdx.x * 64;
  const int wave = t >> 6;
  const int wm = (wave & 1) * 64, wn = (wave >> 1) * 32;
  const int l16 = t & 15, quad = (t >> 4) & 3, l63 = t & 63;
  const int sr = t >> 1, sp = (t & 1) * 16;
  const ushort_t* ah_g = Ahi + (size_t)(m0 + sr) * K + sp;
  const ushort_t* al_g = Alo + (size_t)(m0 + sr) * K + sp;
  const int nb0 = (n0 + wn) >> 4;

  f32x4 acc[4][2];
#pragma unroll
  for (int i = 0; i < 4; ++i)
#pragma unroll
    for (int j = 0; j < 2; ++j) acc[i][j] = (f32x4){0.f, 0.f, 0.f, 0.f};

  uint4 rh0, rh1, rl0, rl1;
  rh0 = *(const uint4*)(ah_g);
  rh1 = *(const uint4*)(ah_g + 8);
  rl0 = *(const uint4*)(al_g);
  rl1 = *(const uint4*)(al_g + 8);
  *(uint4*)&Ah[0][sr][sp] = rh0;
  *(uint4*)&Ah[0][sr][sp + 8] = rh1;
  *(uint4*)&Al[0][sr][sp] = rl0;
  *(uint4*)&Al[0][sr][sp + 8] = rl1;
  __syncthreads();

  for (int kb = 0; kb < kbc; ++kb) {
    const int cur = kb & 1, nxt = cur ^ 1;
    if (kb + 1 < kbc) {
      const ushort_t* ph = ah_g + (kb + 1) * 32;
      const ushort_t* plo = al_g + (kb + 1) * 32;
      rh0 = *(const uint4*)ph;
      rh1 = *(const uint4*)(ph + 8);
      rl0 = *(const uint4*)plo;
      rl1 = *(const uint4*)(plo + 8);
    }
    bf16x8 bh[2], bl[2];
#pragma unroll
    for (int nt = 0; nt < 2; ++nt) {
      size_t o = (((size_t)(nb0 + nt) * kbc + kb) * 64 + l63) * 8;
      bh[nt] = *(const bf16x8*)&Bph[o];
      bl[nt] = *(const bf16x8*)&Bpl[o];
    }
    bf16x8 afh[4], afl[4];
#pragma unroll
    for (int mt = 0; mt < 4; ++mt) {
      afh[mt] = *(const bf16x8*)&Ah[cur][wm + mt * 16 + l16][quad * 8];
      afl[mt] = *(const bf16x8*)&Al[cur][wm + mt * 16 + l16][quad * 8];
    }
#pragma unroll
    for (int mt = 0; mt < 4; ++mt)
#pragma unroll
      for (int nt = 0; nt < 2; ++nt) {
        acc[mt][nt] = __builtin_amdgcn_mfma_f32_16x16x32_bf16(afh[mt], bh[nt], acc[mt][nt], 0, 0, 0);
        acc[mt][nt] = __builtin_amdgcn_mfma_f32_16x16x32_bf16(afh[mt], bl[nt], acc[mt][nt], 0, 0, 0);
        acc[mt][nt] = __builtin_amdgcn_mfma_f32_16x16x32_bf16(afl[mt], bh[nt], acc[mt][nt], 0, 0, 0);
      }
    if (kb + 1 < kbc) {
      *(uint4*)&Ah[nxt][sr][sp] = rh0;
      *(uint4*)&Ah[nxt][sr][sp + 8] = rh1;
      *(uint4*)&Al[nxt][sr][sp] = rl0;
      *(uint4*)&Al[nxt][sr][sp + 8] = rl1;
    }
    __syncthreads();
  }

#pragma unroll
  for (int mt = 0; mt < 4; ++mt)
#pragma unroll
    for (int nt = 0; nt < 2; ++nt)
#pragma unroll
      for (int rg = 0; rg < 4; ++rg) {
        int m = m0 + wm + mt * 16 + quad * 4 + rg;
        int n = n0 + wn + nt * 16 + l16;
        float v = lrelu(acc[mt][nt][rg] + bias[n], slope);
        size_t o = (size_t)m * N + n;
        if (Cf) Cf[o] = v;
        if (Chi) {
          ushort_t h = f2bf(v);
          Chi[o] = h; Clo[o] = f2bf(v - bf2f(h));
        }
      }
}

// ---------------------------------------------------------------------------
// MFMA attention v10: R1 structure (64x4 grid, 1 block/CU, 252/256 unified
// regs -- do NOT raise occupancy, R2 proved acc spills to scratch at 128-reg
// cap) + B-tile staged to LDS via global_load_lds, double-buffered, issued
// ONE kt ahead. Removes per-iter L2/L3 latency of the 8 Bf global loads from
// the critical path (asm barrier prevented hoisting them). Sync: each wave
// waits vmcnt(6) on its OWN stage loads BEFORE the end-of-iter barrier
// (leaves the 6 adj/s2 prefetch loads in flight); barrier then publishes all
// waves' stages. vmcnt(0) on the last two iters (no trailing fetches).
// LDS: W dbuf 32K + B dbuf 64K = 96K, still 1 block/CU.
// ---------------------------------------------------------------------------
__global__ __launch_bounds__(512, 1) void attn_mfma8(
    const ushort_t* __restrict__ Bpack, const float* __restrict__ s1g,
    const float* __restrict__ s2g, const int* __restrict__ adj,
    ushort_t* __restrict__ pacc, float* __restrict__ pl)
{
  __shared__ ushort_t Wlds[2][2][8][64][8];    // [buf][head][mt8][lane][8] 32K
  __shared__ ushort_t Blds[2][2][16][64][8];   // [buf][head][nb][lane][8]  64K
  const int t = threadIdx.x;
  const int i0 = blockIdx.x * 128;
  const int js = blockIdx.y;
  const int kbase = js * 2048;
  // generator mapping: row wr (0..127), k-octet kq (0..3)
  const int wr = t >> 2, kq = t & 3;
  const int glane = kq * 16 + (wr & 15);
  const int gmt = wr >> 4;                    // 0..7
  const float s1v0 = s1g[i0 + wr];
  const float s1v1 = s1g[8192 + i0 + wr];
  // consumer mapping: wave = (head, nh, rowgrp)
  const int wave = t >> 6;
  const int head = wave >> 2, nh = (wave >> 1) & 1, rg2 = wave & 1;
  const int l16 = t & 15, quad = (t >> 4) & 3;
  const int l63 = t & 63;
  f32x4 acc[4][8];
#pragma unroll
  for (int m = 0; m < 4; ++m)
#pragma unroll
    for (int n = 0; n < 8; ++n) acc[m][n] = (f32x4){0.f, 0.f, 0.f, 0.f};
  float rs0 = 0.f, rs1 = 0.f;

  const int* arow = adj + (size_t)(i0 + wr) * 8192;
  int4 pa0, pa1;
  float4 p20a, p20b, p21a, p21b;

  auto fetch = [&](int kk) {
    pa0 = *(const int4*)&arow[kk];
    pa1 = *(const int4*)&arow[kk + 4];
    p20a = *(const float4*)&s2g[kk];
    p20b = *(const float4*)&s2g[kk + 4];
    p21a = *(const float4*)&s2g[8192 + kk];
    p21b = *(const float4*)&s2g[8192 + kk + 4];
  };
  auto gen = [&](int buf) {
    int am[8] = {pa0.x, pa0.y, pa0.z, pa0.w, pa1.x, pa1.y, pa1.z, pa1.w};
    float s20[8] = {p20a.x, p20a.y, p20a.z, p20a.w, p20b.x, p20b.y, p20b.z, p20b.w};
    float s21[8] = {p21a.x, p21a.y, p21a.z, p21a.w, p21b.x, p21b.y, p21b.z, p21b.w};
    ushort_t w0[8] __attribute__((aligned(16)));
    ushort_t w1[8] __attribute__((aligned(16)));
#pragma unroll
    for (int e = 0; e < 8; ++e) {
      float e0 = s1v0 + s20[e];
      float e1 = s1v1 + s21[e];
      e0 = fmaxf(e0, 0.f) + ALPHA * fminf(e0, 0.f);
      e1 = fmaxf(e1, 0.f) + ALPHA * fminf(e1, 0.f);
      float v0 = am[e] > 0 ? __expf(e0) : 0.f;
      float v1 = am[e] > 0 ? __expf(e1) : 0.f;
      rs0 += v0; rs1 += v1;
      w0[e] = f2bf(v0); w1[e] = f2bf(v1);
    }
    *(uint4*)&Wlds[buf][0][gmt][glane][0] = *(uint4*)w0;
    *(uint4*)&Wlds[buf][1][gmt][glane][0] = *(uint4*)w1;
  };
  // Stage the 32KB B tile for kblk into Blds[buf]. Wave w covers head=w>>2,
  // quarter q=w&3 (4KB): 4 x global_load_lds dwordx4; HW writes lane*16B.
  // LDS layout is linear in source order, so consumer indexing matches Bpack.
  auto stageB = [&](int buf, int kblk) {
    const ushort_t* gsrc = Bpack + (((size_t)head * 256 + kblk) << 13)
                           + ((wave & 3) << 11) + (l63 << 3);
    ushort_t* lbase = &Blds[buf][head][0][0][0];
#pragma unroll
    for (int j = 0; j < 4; ++j)
      __builtin_amdgcn_global_load_lds(
          (const __attribute__((address_space(1))) unsigned int*)(gsrc + j * 512),
          (__attribute__((address_space(3))) unsigned int*)
              (lbase + ((wave & 3) << 11) + j * 512),
          16, 0, 0);
  };

  stageB(0, js * 64);
  fetch(kbase + kq * 8);
  gen(0);
  fetch(kbase + 32 + kq * 8);
  __asm__ __volatile__("s_waitcnt vmcnt(6)" ::: "memory");  // own stageB(0) done
  ASM_BARRIER();

  for (int kt = 0; kt < 64; ++kt) {
    const int cur = kt & 1, nxt = cur ^ 1;
    if (kt < 63) stageB(nxt, js * 64 + kt + 1);
    bf16x8 Bf[8];
#pragma unroll
    for (int nt = 0; nt < 8; ++nt)
      Bf[nt] = *(const bf16x8*)&Blds[cur][head][nh * 8 + nt][l63][0];
    bf16x8 Af[4];
#pragma unroll
    for (int mt = 0; mt < 4; ++mt)
      Af[mt] = *(const bf16x8*)&Wlds[cur][head][rg2 * 4 + mt][l63][0];
#pragma unroll
    for (int mt = 0; mt < 4; ++mt)
#pragma unroll
      for (int nt = 0; nt < 8; ++nt)
        acc[mt][nt] = __builtin_amdgcn_mfma_f32_16x16x32_bf16(
            Af[mt], Bf[nt], acc[mt][nt], 0, 0, 0);
    if (kt < 63) {
      gen(nxt);
      if (kt < 62) fetch(kbase + (kt + 2) * 32 + kq * 8);
    }
    // wait own stage loads (issued this iter) before publishing barrier;
    // vmcnt(6) leaves the 6 adj/s2 prefetch loads in flight.
    if (kt < 62) { __asm__ __volatile__("s_waitcnt vmcnt(6)" ::: "memory"); }
    else         { __asm__ __volatile__("s_waitcnt vmcnt(0)" ::: "memory"); }
    ASM_BARRIER();
  }

  // denominators: reduce across the 4 kq lanes of each row
  rs0 += __shfl_xor(rs0, 1); rs0 += __shfl_xor(rs0, 2);
  rs1 += __shfl_xor(rs1, 1); rs1 += __shfl_xor(rs1, 2);
  if (kq == 0) {
    pl[((size_t)js * 2 + 0) * 8192 + i0 + wr] = rs0;
    pl[((size_t)js * 2 + 1) * 8192 + i0 + wr] = rs1;
  }
  // store bf16 partial numerators
  const int n0 = nh * 128;
#pragma unroll
  for (int mt = 0; mt < 4; ++mt)
#pragma unroll
    for (int nt = 0; nt < 8; ++nt)
#pragma unroll
      for (int rg = 0; rg < 4; ++rg) {
        int row = i0 + rg2 * 64 + mt * 16 + quad * 4 + rg;
        int col = n0 + nt * 16 + l16;
        pacc[(((size_t)js * 2 + head) * 8192 + row) * 256 + col] =
            f2bf(acc[mt][nt][rg]);
      }
}

// ---------------------------------------------------------------------------
// Finalize (R9, frozen): emits embed directly as hi/lo bf16 split.
// ---------------------------------------------------------------------------
__global__ __launch_bounds__(256) void attn_finalize(
    const ushort_t* __restrict__ pacc, const float* __restrict__ pl,
    const float* __restrict__ bg, const float* __restrict__ llm,
    ushort_t* __restrict__ ehi, ushort_t* __restrict__ elo)
{
  __shared__ float red[8];
  const int r = blockIdx.x;
  const int t = threadIdx.x;
  const int wv = t >> 6, lane = t & 63;
#pragma unroll
  for (int half = 0; half < 2; ++half) {
    float lv = llm[(size_t)r * 512 + half * 256 + t];
    ushort_t h = f2bf(lv);
    ehi[(size_t)r * 768 + half * 256 + t] = h;
    elo[(size_t)r * 768 + half * 256 + t] = f2bf(lv - bf2f(h));
  }
  float o[2];
#pragma unroll
  for (int hh = 0; hh < 2; ++hh) {
    float num = 0.f, l = 0.f;
#pragma unroll
    for (int js = 0; js < 4; ++js) {
      num += bf2f(pacc[(((size_t)js * 2 + hh) * 8192 + r) * 256 + t]);
      l += pl[((size_t)js * 2 + hh) * 8192 + r];
    }
    o[hh] = lrelu(num / l, ALPHA);
  }
  float v0 = o[0] * o[0], v1 = o[1] * o[1];
  for (int off = 32; off > 0; off >>= 1) {
    v0 += __shfl_xor(v0, off);
    v1 += __shfl_xor(v1, off);
  }
  if (lane == 0) { red[wv] = v0; red[4 + wv] = v1; }
  __syncthreads();
  float n0 = fmaxf(sqrtf(red[0] + red[1] + red[2] + red[3]), 1e-12f);
  float n1 = fmaxf(sqrtf(red[4] + red[5] + red[6] + red[7]), 1e-12f);
  float val = 0.5f * (o[0] / n0 + bg[t] + o[1] / n1 + bg[256 + t]);
  ushort_t h = f2bf(val);
  ehi[(size_t)r * 768 + 512 + t] = h;
  elo[(size_t)r * 768 + 512 + t] = f2bf(val - bf2f(h));
}

// ---------------------------------------------------------------------------
__global__ __launch_bounds__(256) void pred_kernel(
    const float* __restrict__ z2, const int* __restrict__ ts,
    float* __restrict__ out, int E)
{
  const int gw = (blockIdx.x * 256 + threadIdx.x) >> 6;
  const int lane = threadIdx.x & 63;
  if (gw >= E) return;
  const int a = ts[gw * 2], b = ts[gw * 2 + 1];
  float4 va = ((const float4*)(z2 + (size_t)a * 256))[lane];
  float4 vb = ((const float4*)(z2 + (size_t)b * 256))[lane];
  float p = va.x * vb.x + va.y * vb.y + va.z * vb.z + va.w * vb.w;
  for (int off = 32; off > 0; off >>= 1) p += __shfl_xor(p, off);
  if (lane == 0) out[gw] = p;
}

// ---------------------------------------------------------------------------
extern "C" void kernel_launch(void* const* d_in, const int* in_sizes, int n_in,
                              void* d_out, int out_size, void* d_ws, size_t ws_size,
                              hipStream_t stream) {
  const float* x   = (const float*)d_in[0];
  const int*   adj = (const int*)d_in[1];
  const int*   ts  = (const int*)d_in[2];
  const float* llm = (const float*)d_in[3];
  const float* Wg  = (const float*)d_in[4];
  const float* a1  = (const float*)d_in[5];
  const float* a2  = (const float*)d_in[6];
  const float* bg  = (const float*)d_in[7];
  const float* W1  = (const float*)d_in[8];
  const float* b1  = (const float*)d_in[9];
  const float* W2  = (const float*)d_in[10];
  const float* b2  = (const float*)d_in[11];
  float* out = (float*)d_out;
  float* ws  = (float*)d_ws;
  const int E = in_sizes[2] / 2;

  // ---- workspace layout (float words) ----
  ushort_t* xb    = (ushort_t*)(ws + 0);            //  8192x512 bf16
  ushort_t* Wgp   = (ushort_t*)(ws + 2097152);      //  2x512x256
  ushort_t* W1ph  = (ushort_t*)(ws + 2228224);      //  768x512
  ushort_t* W1pl  = (ushort_t*)(ws + 2424832);
  ushort_t* W2ph  = (ushort_t*)(ws + 2621440);      //  512x256
  ushort_t* W2pl  = (ushort_t*)(ws + 2686976);
  ushort_t* Bpack = (ushort_t*)(ws + 2752512);      //  2x8192x256
  float*    s1    = ws + 4849664;                   //  2x8192
  float*    s2    = ws + 4866048;
  float*    pl    = ws + 4882432;                   //  8x8192
  ushort_t* pacc  = (ushort_t*)(ws + 4947968);      //  8x8192x256
  ushort_t* ehi   = (ushort_t*)(ws + 13336576);     //  8192x768
  ushort_t* elo   = (ushort_t*)(ws + 16482304);
  ushort_t* z1hi  = (ushort_t*)(ws + 19628032);     //  8192x512
  ushort_t* z1lo  = (ushort_t*)(ws + 21725184);
  float*    z2    = ws + 23822336;                  //  8192x256 f32

  // 1. prep: casts, weight packing, s-zero
  tobf<<<4096, 256, 0, stream>>>(x, xb);
  pack_wt<<<dim3(64, 2), 256, 0, stream>>>(Wg, Wgp, nullptr, 512, 256);
  pack_wt<<<dim3(192, 1), 256, 0, stream>>>(W1, W1ph, W1pl, 768, 512);
  pack_wt<<<dim3(64, 1), 256, 0, stream>>>(W2, W2ph, W2pl, 512, 256);
  zero_f<<<32, 256, 0, stream>>>(s1);   // covers s1 and s2 (contiguous)
  // 2. fused h-GEMM -> Bpack + s1/s2 (hbuf never materialized)
  gemm_h<<<dim3(4, 64, 2), 256, 0, stream>>>(xb, Wgp, a1, a2, Bpack, s1, s2);
  // 3. MFMA attention partials (128-row blocks, B tile via LDS prefetch)
  attn_mfma8<<<dim3(64, 4), 512, 0, stream>>>(Bpack, s1, s2, adj, pacc, pl);
  // 4. finalize -> embed emitted directly as hi/lo split (llm inline)
  attn_finalize<<<8192, 256, 0, stream>>>(pacc, pl, bg, llm, ehi, elo);
  // 5. z1 = LR(embed @ W1 + b1) -> hi/lo
  gemm_mlp<<<dim3(8, 64), 256, 0, stream>>>(
      ehi, elo, W1ph, W1pl, b1, nullptr, z1hi, z1lo, 8192, 512, 768, MLP_SLOPE);
  // 6. z2 = LR(z1 @ W2 + b2) -> fp32
  gemm_mlp<<<dim3(4, 64), 256, 0, stream>>>(
      z1hi, z1lo, W2ph, W2pl, b2, z2, nullptr, nullptr, 8192, 256, 512, MLP_SLOPE);
  // 7. edge dots
  pred_kernel<<<(E * 64 + 255) / 256, 256, 0, stream>>>(z2, ts, out, E);
}